// Round 5
// baseline (325.666 us; speedup 1.0000x reference)
//
#include <hip/hip_runtime.h>

#define T_SIZE 4194304
#define B_SIZE 131072
#define KD 8
#define TBL_V4 (T_SIZE * KD / 4)   // 8,388,608 float4 in the table
#define SCR_V4 (T_SIZE / 4)        // 1,048,576 float4 in scores / longevity

typedef unsigned long long u64;
typedef unsigned int u32;
// Native clang vector — required by __builtin_nontemporal_* (HIP float4 is a
// class and is rejected). Same 16B size/alignment.
typedef float f32x4 __attribute__((ext_vector_type(4)));

// K1: targeted clear. Only ~3% of slots are ever touched; clearing just those
// (plain 8B stores, duplicate stores benign — all write 0) replaces the 32 MB
// full-array memset. Kernel boundary makes the stores visible to K2's atomics.
__global__ void vault_clear_kernel(const int* __restrict__ indices,
                                   u64* __restrict__ packed) {
    int i = blockIdx.x * blockDim.x + threadIdx.x;
    packed[indices[i]] = 0ull;
}

// K2: argmax scatter. packed = (surv_bits<<32) | ~row.
// surv >= 0 so float-bit order == numeric order; atomicMax computes per slot
// the max survivorship AND, among ties, the minimum row (first-winner rule).
// Every real row packs > 0 (row < 2^17 -> ~row >= 0xFFFE0000), so 0 is identity.
__global__ void vault_scatter_kernel(const float* __restrict__ survivorship,
                                     const int* __restrict__ indices,
                                     u64* __restrict__ packed) {
    int i = blockIdx.x * blockDim.x + threadIdx.x;
    int idx = indices[i];
    u32 bits = __float_as_uint(survivorship[i]);
    u64 p = ((u64)bits << 32) | (u64)(~(u32)i);
    atomicMax(packed + idx, p);
}

// K3: pure streaming bulk pass — the ONLY full-T traffic in the pipeline.
// Flat float4 copy: new_table = trust_table, new_scores = trust_scores,
// new_longevity = (float)longevity. Lane-contiguous 16B/lane, no packed read,
// no divergence (region boundaries are multiples of the block size).
// K4 later patches the <=131k touched slots.
__global__ void vault_bulk_kernel(const float* __restrict__ trust_table,
                                  const float* __restrict__ trust_scores,
                                  const int* __restrict__ longevity,
                                  float* __restrict__ new_table,
                                  float* __restrict__ new_scores,
                                  float* __restrict__ new_longevity) {
    int i = blockIdx.x * blockDim.x + threadIdx.x;
    if (i < TBL_V4) {
        f32x4 v = __builtin_nontemporal_load((const f32x4*)trust_table + i);
        __builtin_nontemporal_store(v, (f32x4*)new_table + i);
    } else if (i < TBL_V4 + SCR_V4) {
        int j = i - TBL_V4;
        f32x4 v = __builtin_nontemporal_load((const f32x4*)trust_scores + j);
        __builtin_nontemporal_store(v, (f32x4*)new_scores + j);
    } else {
        int j = i - (TBL_V4 + SCR_V4);
        int4 l = ((const int4*)longevity)[j];
        ((float4*)new_longevity)[j] =
            make_float4((float)l.x, (float)l.y, (float)l.z, (float)l.w);
    }
}

// K4: per-row patch (runs after K3, ordering via stream).
//  - query_scores[i] = max(old_score, slot max survivorship)
//  - longevity count via fp32 atomicAdd on the converted base (exact, ints)
//  - the unique winner row (argmax-min-row AND strictly beats old score)
//    overwrites its slot's table row and score.
__global__ void vault_patch_kernel(const float* __restrict__ residues,
                                   const float* __restrict__ trust_scores,
                                   const int* __restrict__ indices,
                                   const u64* __restrict__ packed,
                                   float* __restrict__ query_scores,
                                   float* __restrict__ new_table,
                                   float* __restrict__ new_scores,
                                   float* __restrict__ new_longevity) {
    int i = blockIdx.x * blockDim.x + threadIdx.x;
    int idx = indices[i];
    u64 p = packed[idx];
    float ms = __uint_as_float((u32)(p >> 32));
    float oldv = trust_scores[idx];
    query_scores[i] = fmaxf(oldv, ms);
    atomicAdd(new_longevity + idx, 1.0f);
    if (ms > oldv && (int)(~(u32)p) == i) {   // unique winner for this slot
        new_scores[idx] = ms;
        const float4* src = (const float4*)(residues + (size_t)i * KD);
        float4 a = src[0];
        float4 c = src[1];
        float4* dst = (float4*)(new_table + (size_t)idx * KD);
        dst[0] = a;
        dst[1] = c;
    }
}

extern "C" void kernel_launch(void* const* d_in, const int* in_sizes, int n_in,
                              void* d_out, int out_size, void* d_ws, size_t ws_size,
                              hipStream_t stream) {
    const float* residues      = (const float*)d_in[0];   // [B, 8]
    const float* survivorship  = (const float*)d_in[1];   // [B]
    const float* trust_table   = (const float*)d_in[2];   // [T, 8]
    const float* trust_scores  = (const float*)d_in[3];   // [T]
    const int*   longevity     = (const int*)d_in[4];     // [T]
    const int*   indices       = (const int*)d_in[5];     // [B]

    // Output layout (concatenated flat, return order, ALL read back as float32):
    // query_scores [B] | new_table [T*8] | new_scores [T] | new_longevity [T]
    float* query_scores  = (float*)d_out;
    float* new_table     = query_scores + B_SIZE;
    float* new_scores    = new_table + (size_t)T_SIZE * KD;
    float* new_longevity = new_scores + T_SIZE;

    u64* packed = (u64*)d_ws;  // [T] scratch (32 MB), poisoned each iter;
                               // only touched slots are cleared (K1).

    const int blk = 256;

    // 1) clear packed at touched slots only
    vault_clear_kernel<<<B_SIZE / blk, blk, 0, stream>>>(indices, packed);

    // 2) argmax atomic scatter
    vault_scatter_kernel<<<B_SIZE / blk, blk, 0, stream>>>(
        survivorship, indices, packed);

    // 3) pure streaming bulk copy (table + scores + longevity conversion)
    vault_bulk_kernel<<<(TBL_V4 + 2 * SCR_V4) / blk, blk, 0, stream>>>(
        trust_table, trust_scores, longevity,
        new_table, new_scores, new_longevity);

    // 4) per-row patch: query gather + longevity counts + winner rewrites
    vault_patch_kernel<<<B_SIZE / blk, blk, 0, stream>>>(
        residues, trust_scores, indices, packed,
        query_scores, new_table, new_scores, new_longevity);
}